// Round 5
// baseline (185.439 us; speedup 1.0000x reference)
//
#include <hip/hip_runtime.h>

#define B_   16
#define C_   64
#define N_   2048
#define M_   (B_ * N_)     // 32768 points
#define K_   20
#define KS_  20
#define OC_  64
#define NW2  8192          // waves in k_points (4 points each)

// ---------------------------------------------------------------------------
// K1: P[m][o] = sum_c W2[o][c]*flat[m][c];  Q[m][o] = sum_c (W1-W2)[o][c]*flat[m][c]
// wave = 64 lanes, lane = o. Weights in 128 VGPRs, feature broadcast via
// readlane. 8 points/wave -> 1024 blocks (4/CU).
// ---------------------------------------------------------------------------
__global__ __launch_bounds__(256) void k_project(
    const float* __restrict__ feat,     // [B][C][N]
    const float* __restrict__ conv_w,   // [OC][2C]
    float* __restrict__ pq)             // [M][128]
{
    const int lane = threadIdx.x & 63;
    const int wg   = blockIdx.x * 4 + (threadIdx.x >> 6);   // 0..4095
    float w2[64], wd[64];
    const float4* cw4 = (const float4*)conv_w;
    #pragma unroll
    for (int j = 0; j < 16; ++j) {
        float4 a = cw4[lane * 32 + j];        // W1 chunk
        float4 b = cw4[lane * 32 + 16 + j];   // W2 chunk
        w2[4*j+0] = b.x; w2[4*j+1] = b.y; w2[4*j+2] = b.z; w2[4*j+3] = b.w;
        wd[4*j+0] = a.x - b.x; wd[4*j+1] = a.y - b.y;
        wd[4*j+2] = a.z - b.z; wd[4*j+3] = a.w - b.w;
    }
    const int m0 = wg * 8;
    int b0 = m0 >> 11, p0 = m0 & 2047;
    float fv = feat[((size_t)(b0 * 64 + lane)) * 2048 + p0];
    for (int mi = 0; mi < 8; ++mi) {
        const int m = m0 + mi;
        float fnext = 0.f;
        if (mi < 7) {
            const int mn = m + 1;
            fnext = feat[((size_t)((mn >> 11) * 64 + lane)) * 2048 + (mn & 2047)];
        }
        float p0a = 0.f, p1a = 0.f, q0a = 0.f, q1a = 0.f;
        #pragma unroll
        for (int c = 0; c < 32; ++c) {
            float f0 = __int_as_float(
                __builtin_amdgcn_readlane(__float_as_int(fv), c));
            float f1 = __int_as_float(
                __builtin_amdgcn_readlane(__float_as_int(fv), c + 32));
            p0a = fmaf(w2[c], f0, p0a);
            p1a = fmaf(w2[c + 32], f1, p1a);
            q0a = fmaf(wd[c], f0, q0a);
            q1a = fmaf(wd[c + 32], f1, q1a);
        }
        pq[(size_t)m * 128 + lane]      = p0a + p1a;
        pq[(size_t)m * 128 + 64 + lane] = q0a + q1a;
        fv = fnext;
    }
}

// ---------------------------------------------------------------------------
// K2: 4 points per wave. lane = p*16+og; p = point-in-group, og = o-group,
// lane covers channels o = og*4..og*4+3 (float4 everywhere).
//  - perm staged via plain global float4 loads + ds_write_b128 into padded
//    404-float slots (NO global_load_lds: its implied lane addressing with
//    multiple bases + predicated exec is one of two R3/R4 bug candidates).
//  - __syncthreads() fences staging vs the uniform ds_read_b128 broadcasts.
//  - 25 ds_read_b128/point; the 4 groups' broadcasts hit disjoint bank
//    quads (base offsets 0,20,8,28 mod 32).
//  - pq gathers: dwordx4, 4 x 256B segments per instr; per-k prefetch.
// ---------------------------------------------------------------------------
__global__ __launch_bounds__(256) void k_points(
    const float* __restrict__ pq,        // [M][128]
    const int*   __restrict__ nidx,      // [M][K]
    const float* __restrict__ perm,      // [M][K][KS]
    const float* __restrict__ conv_b,    // [OC]
    float* __restrict__ pre,             // [M][OC]
    float* __restrict__ partials)        // [NW2][128]
{
    __shared__ __align__(16) float plds[4 * 4 * 404];   // 25.9 KB
    const int tid  = threadIdx.x;
    const int lane = tid & 63;
    const int og   = lane & 15;
    const int p    = lane >> 4;
    const int wv   = tid >> 6;
    const int wg   = (int)blockIdx.x * 4 + wv;    // 0..8191
    const int nb   = wg * 4;
    const int n    = nb + p;                      // this lane's point
    float* wbuf = &plds[wv * 1616];

    // idx rows for 4 points: 80 contiguous ints as int2 across lanes 0..39
    int2 iv2 = make_int2(0, 0);
    if (lane < 40) iv2 = ((const int2*)(nidx + (size_t)nb * 20))[lane];

    // stage 4 perm rows (400 floats each) into padded slots (stride 404):
    // explicit load + ds_write, fully compiler-managed addressing/waits.
    #pragma unroll
    for (int pp = 0; pp < 4; ++pp) {
        const float4* src = (const float4*)(perm + (size_t)(nb + pp) * 400);
        float* dst = wbuf + pp * 404;
        float4 v0 = src[lane];
        *(float4*)(dst + lane * 4) = v0;
        if (lane < 36) {
            float4 v1 = src[64 + lane];
            *(float4*)(dst + 256 + lane * 4) = v1;
        }
    }

    const float4 bias = *(const float4*)(conv_b + og * 4);

    // k=0 index -> q gather + first pk gather (may overlap the staging)
    int ik0 = __shfl(iv2.x, p * 10);              // flat (p*20+0): lane p*10, comp x
    const float* pqb = pq + (size_t)ik0 * 128 + og * 4;
    float4 q4  = *(const float4*)(pqb + 64);
    float4 pkc = *(const float4*)(pqb);

    // fence: staging ds_writes visible before the broadcasts below.
    __syncthreads();

    float acc[4][20];
    #pragma unroll
    for (int s = 0; s < 20; ++s) {
        acc[0][s] = bias.x; acc[1][s] = bias.y;
        acc[2][s] = bias.z; acc[3][s] = bias.w;
    }

    const float* gbase = wbuf + p * 404;          // this lane's perm row in LDS
    #pragma unroll
    for (int k = 0; k < 20; ++k) {
        // prefetch next pk gather
        float4 pkn = pkc;
        if (k < 19) {
            const int kk = k + 1;
            int src = p * 10 + (kk >> 1);         // flat (p*20+kk) >> 1
            int ikn = (kk & 1) ? __shfl(iv2.y, src) : __shfl(iv2.x, src);
            pkn = *(const float4*)(pq + (size_t)ikn * 128 + og * 4);
        }
        float t[4];
        t[0] = pkc.x + q4.x; t[1] = pkc.y + q4.y;
        t[2] = pkc.z + q4.z; t[3] = pkc.w + q4.w;
        #pragma unroll
        for (int c = 0; c < 5; ++c) {
            float4 m4 = *(const float4*)(gbase + k * 20 + c * 4);
            #pragma unroll
            for (int j = 0; j < 4; ++j) {
                acc[j][c*4+0] = fmaf(t[j], m4.x, acc[j][c*4+0]);
                acc[j][c*4+1] = fmaf(t[j], m4.y, acc[j][c*4+1]);
                acc[j][c*4+2] = fmaf(t[j], m4.z, acc[j][c*4+2]);
                acc[j][c*4+3] = fmaf(t[j], m4.w, acc[j][c*4+3]);
            }
        }
        pkc = pkn;
    }

    float mv[4];
    #pragma unroll
    for (int j = 0; j < 4; ++j) {
        float m = acc[j][0];
        #pragma unroll
        for (int s = 1; s < 20; ++s) m = fmaxf(m, acc[j][s]);
        mv[j] = m;
    }
    *(float4*)(pre + (size_t)n * 64 + og * 4) = make_float4(mv[0], mv[1], mv[2], mv[3]);

    // BN partial sums per channel: reduce across the 4 point-groups
    float sv[4], sw[4];
    #pragma unroll
    for (int j = 0; j < 4; ++j) {
        float v = mv[j], w = mv[j] * mv[j];
        v += __shfl_xor(v, 16); v += __shfl_xor(v, 32);
        w += __shfl_xor(w, 16); w += __shfl_xor(w, 32);
        sv[j] = v; sw[j] = w;
    }
    if (lane < 16) {
        *(float4*)(partials + (size_t)wg * 128 + lane * 4)
            = make_float4(sv[0], sv[1], sv[2], sv[3]);
        *(float4*)(partials + (size_t)wg * 128 + 64 + lane * 4)
            = make_float4(sw[0], sw[1], sw[2], sw[3]);
    }
}

// ---------------------------------------------------------------------------
// K2b stage A: coalesced reduce. block b sums 64 partials rows -> mid[b][128]
// ---------------------------------------------------------------------------
__global__ __launch_bounds__(256) void k_red1(
    const float* __restrict__ partials,  // [NW2][128]
    float* __restrict__ mid)             // [128][128]
{
    const int t = threadIdx.x;
    const int c = t & 127, rh = t >> 7;
    const float* base = partials + (size_t)blockIdx.x * 64 * 128;
    float s = 0.f;
    for (int i = rh; i < 64; i += 2) s += base[(size_t)i * 128 + c];
    __shared__ float sh[256];
    sh[t] = s;
    __syncthreads();
    if (t < 128) mid[(size_t)blockIdx.x * 128 + t] = sh[t] + sh[t + 128];
}

// ---------------------------------------------------------------------------
// K2b stage B: final fp64 reduce + fold BN/gamma/beta into scale/shift.
// ---------------------------------------------------------------------------
__global__ __launch_bounds__(256) void k_red2(
    const float* __restrict__ mid,       // [128][128]
    const float* __restrict__ gamma,
    const float* __restrict__ beta,
    float* __restrict__ stats)           // [128]
{
    const int t = threadIdx.x;
    const int c = t & 127, rh = t >> 7;
    double s = 0.0;
    for (int i = rh; i < 128; i += 2) s += (double)mid[(size_t)i * 128 + c];
    __shared__ double shd[256];
    __shared__ double tot[128];
    shd[t] = s;
    __syncthreads();
    if (t < 128) tot[t] = shd[t] + shd[t + 128];
    __syncthreads();
    if (t < 64) {
        const double inv_n = 1.0 / (double)M_;
        double mean = tot[t] * inv_n;
        double var  = tot[t + 64] * inv_n - mean * mean;
        double inv  = 1.0 / sqrt(var + 1e-5);
        double sc   = (double)gamma[t] * inv;
        stats[t]      = (float)sc;
        stats[64 + t] = (float)((double)beta[t] - mean * sc);
    }
}

// ---------------------------------------------------------------------------
// K3: y = pre*scale + shift, transposed [M][OC] -> [B][OC][N] via LDS 64x65.
// ---------------------------------------------------------------------------
__global__ __launch_bounds__(256) void k_apply(
    const float* __restrict__ pre,     // [M][OC]
    const float* __restrict__ stats,   // [128]
    float* __restrict__ out)           // [B][OC][N]
{
    __shared__ float tile[64 * 65];
    __shared__ float scl[64];
    __shared__ float shf[64];
    const int tid = threadIdx.x;
    if (tid < 64)       scl[tid]      = stats[tid];
    else if (tid < 128) shf[tid - 64] = stats[tid];
    __syncthreads();
    const int b  = blockIdx.x >> 5;
    const int pt = (blockIdx.x & 31) * 64;
    const int c  = tid & 63;
    const int r0 = tid >> 6;
    #pragma unroll
    for (int i = 0; i < 16; ++i) {
        const int r = i * 4 + r0;
        float v = pre[((size_t)(b * 2048 + pt + r)) * 64 + c];
        tile[c * 65 + r] = fmaf(v, scl[c], shf[c]);
    }
    __syncthreads();
    #pragma unroll
    for (int i = 0; i < 16; ++i) {
        const int o = i * 4 + r0;
        out[((size_t)(b * 64 + o)) * 2048 + pt + c] = tile[o * 65 + c];
    }
}

extern "C" void kernel_launch(void* const* d_in, const int* in_sizes, int n_in,
                              void* d_out, int out_size, void* d_ws, size_t ws_size,
                              hipStream_t stream) {
    const float* feat   = (const float*)d_in[0];
    const int*   nidx   = (const int*)  d_in[1];
    const float* perm   = (const float*)d_in[2];
    const float* conv_w = (const float*)d_in[3];
    const float* conv_b = (const float*)d_in[4];
    const float* gamma  = (const float*)d_in[5];
    const float* beta   = (const float*)d_in[6];
    float* out = (float*)d_out;

    // Workspace layout: byte-identical footprint to the R1/R2 proven-safe
    // bound (28.33 MB). mid/stats alias the pq region, which is dead after
    // k_points (stream order: k_project -> k_points -> k_red1 -> k_red2 ->
    // k_apply; k_apply reads only pre+stats).
    char* ws = (char*)d_ws;
    size_t off = 0;
    float* pq       = (float*)(ws + off); off += (size_t)M_ * 128 * 4;   // 16 MiB
    float* pre      = (float*)(ws + off); off += (size_t)M_ * 64 * 4;    //  8 MiB
    float* partials = (float*)(ws + off); off += (size_t)NW2 * 128 * 4;  //  4 MiB
    float* mid      = pq;                       // 64 KiB, reuses dead pq
    float* stats    = pq + 128 * 128;           // right after mid, still in pq

    hipLaunchKernelGGL(k_project, dim3(1024), dim3(256), 0, stream, feat, conv_w, pq);
    hipLaunchKernelGGL(k_points,  dim3(2048), dim3(256), 0, stream, pq, nidx, perm,
                       conv_b, pre, partials);
    hipLaunchKernelGGL(k_red1,    dim3(128),  dim3(256), 0, stream, partials, mid);
    hipLaunchKernelGGL(k_red2,    dim3(1),    dim3(256), 0, stream, mid, gamma,
                       beta, stats);
    hipLaunchKernelGGL(k_apply,   dim3(512),  dim3(256), 0, stream, pre, stats, out);
}